// Round 12
// baseline (423.423 us; speedup 1.0000x reference)
//
#include <hip/hip_runtime.h>

// ShiftAddNet BasicBlock, N=64, C=planes=128, H=W=32, fp32.
// R12: (1) adder with PZ-guarded padded LDS (stride 36, guard rows+cols):
// window = b128 + 2x b32 reads, zero DPP/cndmask VALU; reg-staged T14
// (load early / ds_write late). (2) launch fusion: prep inside transform<0>,
// finalize_bn folded into transform<1> and bn_add_relu. 7 launches total.

#define NB   64
#define CIN  128
#define HW   32
#define COUT 128
constexpr int PLANE    = HW * HW;        // 1024
constexpr int NPAIR    = CIN / 2;        // 64 packed ci-pair planes (adder)
constexpr int CI_CHUNK = 4;              // fallback conv only
constexpr int CO_CHUNK = 8;              // fallback conv only
constexpr int LPLANE   = 34 * 32;        // fallback conv LDS layout
constexpr int LDS_TOT  = 2 * CI_CHUNK * LPLANE;
constexpr int A_CO     = 4;              // adder co per block
constexpr int ASTRIDE  = 36;             // adder LDS row stride (dwords)
constexpr float FSCALE    = 32768.0f;
constexpr float INV_SCALE = 1.0f / 32768.0f;
constexpr float QS     = 2048.0f;
constexpr float QB     = 32768.5f;
constexpr float INV_QS = 1.0f / 2048.0f;
constexpr unsigned PZ  = 0x80008000u;

// G (fp16 act) layout: [n][ciq(4)][gr(34)][w(32)][sg(4)][8 f16]
constexpr int G_ROWB   = 32 * 4 * 16;            // 2048 B per row
constexpr int G_CIQB   = 34 * G_ROWB;            // 69632 B
constexpr int G_NB     = 4 * G_CIQB;             // 278528 B per image

typedef _Float16 f16x8 __attribute__((ext_vector_type(8)));
typedef float    f32x4 __attribute__((ext_vector_type(4)));

#define GLOBAL_AS __attribute__((address_space(1)))
#define LDS_AS    __attribute__((address_space(3)))

__device__ __forceinline__ int fsw(int w) { return (w & 3) ^ ((w >> 2) & 3); }

__device__ __forceinline__ void gload_lds16(const void* g, void* l) {
    __builtin_amdgcn_global_load_lds((const GLOBAL_AS void*)g, (LDS_AS void*)l,
                                     16, 0, 0);
}
__device__ __forceinline__ float dpp_prev(float x) {
    return __int_as_float(__builtin_amdgcn_update_dpp(
        0, __float_as_int(x), 0x111, 0xF, 0xF, true));
}
__device__ __forceinline__ float dpp_next(float x) {
    return __int_as_float(__builtin_amdgcn_update_dpp(
        0, __float_as_int(x), 0x101, 0xF, 0xF, true));
}
__device__ __forceinline__ unsigned dpp_prev_u(unsigned x) {
    return (unsigned)__builtin_amdgcn_update_dpp(0, (int)x, 0x111, 0xF, 0xF, true);
}
__device__ __forceinline__ unsigned dpp_next_u(unsigned x) {
    return (unsigned)__builtin_amdgcn_update_dpp(0, (int)x, 0x101, 0xF, 0xF, true);
}
__device__ __forceinline__ uint4 dpp4_shr(uint4 v) {
    uint4 r;
    r.x = dpp_prev_u(v.x); r.y = dpp_prev_u(v.y);
    r.z = dpp_prev_u(v.z); r.w = dpp_prev_u(v.w);
    return r;
}
__device__ __forceinline__ uint4 dpp4_shl(uint4 v) {
    uint4 r;
    r.x = dpp_next_u(v.x); r.y = dpp_next_u(v.y);
    r.z = dpp_next_u(v.z); r.w = dpp_next_u(v.w);
    return r;
}
__device__ __forceinline__ void stage_plane4(const void* src, void* dst, int lane) {
#pragma unroll
    for (int i = 0; i < 4; ++i)
        gload_lds16((const char*)src + i * 1024 + lane * 16,
                    (char*)dst + 128 + i * 1024);
}
__device__ __forceinline__ unsigned q16(float a) {
    float t = fmaf(a, QS, QB);
    t = fminf(fmaxf(t, 0.0f), 65535.0f);
    return (unsigned)t;
}
__device__ __forceinline__ unsigned short f16b(float v) {
    return __builtin_bit_cast(unsigned short, (_Float16)v);
}

// ============================================================ MFMA conv path
// transform: fp32 NCHW (+optional in-kernel BN from raw stats) -> fp16 -> G.
// WITH_BN=0 variant also absorbs the weight-prep work in blocks >= 2048.
template <int WITH_BN>
__global__ __launch_bounds__(256) void transform_split(
    const float* __restrict__ in,
    const double* __restrict__ st, const float* __restrict__ gamma,
    const float* __restrict__ beta, uint4* __restrict__ G,
    const float* __restrict__ a1, const float* __restrict__ a2,
    const float* __restrict__ s1w, const float* __restrict__ s2w,
    unsigned* __restrict__ wqo, unsigned* __restrict__ WFd,
    double* __restrict__ stz)
{
    __shared__ float sT[32 * 132];
    __shared__ float sSC[32], sBI[32];
    const int tid = threadIdx.x;
    const int b   = blockIdx.x;

    if (!WITH_BN && b >= 2048) {             // fused weight prep + stats zero
        if (b == 2048) { stz[tid] = 0.0; stz[tid + 256] = 0.0; }
        int i = (b - 2048) * 256 + tid;      // < 294912
        if (i < 147456) {                    // adder weights (u16 pair)
            int layer = i >= 73728;
            int j   = i - layer * 73728;
            int co  = j / 576;
            int rem = j - co * 576;
            int cp  = rem / 9;
            int tap = rem - cp * 9;
            const float* w = layer ? a2 : a1;
            float f0 = w[((size_t)co * CIN + 2 * cp) * 9 + tap];
            float f1 = w[((size_t)co * CIN + 2 * cp + 1) * 9 + tap];
            wqo[i] = q16(f0) | (q16(f1) << 16);
        } else {                             // conv weights (fp16 A-frags)
            int j = i - 147456;
            int layer = j >= 73728;
            int idx = j - layer * 73728;
            int j2  = idx & 3;
            int l   = (idx >> 2) & 63;
            int cot = (idx >> 8) & 7;
            int ciq = (idx >> 11) & 3;
            int tap = idx >> 13;
            int ci  = ciq * 32 + (l >> 4) * 8 + j2 * 2;
            int co  = cot * 16 + (l & 15);
            const float* w = layer ? s2w : s1w;
            unsigned lo = f16b(w[((size_t)co * CIN + ci) * 9 + tap]);
            unsigned hi = f16b(w[((size_t)co * CIN + ci + 1) * 9 + tap]);
            WFd[layer * 73728 + idx] = lo | (hi << 16);
        }
        return;
    }

    const int n   = b >> 5;
    const int ciq = (b >> 3) & 3;
    const int rq  = b & 7;

    if (WITH_BN) {                           // in-kernel finalize_bn (32 ch)
        if (tid < 32) {
            int ch = ciq * 32 + tid;
            double m   = st[ch] / 65536.0;
            double var = st[128 + ch] / 65536.0 - m * m;
            double rstd = 1.0 / sqrt(var + 1e-5);
            float sc = (float)((double)gamma[ch] * rstd);
            sSC[tid] = sc;
            sBI[tid] = beta[ch] - (float)m * sc;
        }
        __syncthreads();
    }

#pragma unroll
    for (int it = 0; it < 4; ++it) {
        int flat = it * 256 + tid;
        int ci_rel = flat >> 5;
        int px4 = (flat & 31) * 4;
        const float* ap = in + ((size_t)(n * CIN + ciq * 32 + ci_rel)) * PLANE
                             + rq * 128 + px4;
        float4 v = *reinterpret_cast<const float4*>(ap);
        if (WITH_BN) {
            float sc = sSC[ci_rel], bs = sBI[ci_rel];
            v.x = fmaxf(fmaf(v.x, sc, bs), 0.0f);
            v.y = fmaxf(fmaf(v.y, sc, bs), 0.0f);
            v.z = fmaxf(fmaf(v.z, sc, bs), 0.0f);
            v.w = fmaxf(fmaf(v.w, sc, bs), 0.0f);
        }
        v.x = rintf(v.x * FSCALE) * INV_SCALE;
        v.y = rintf(v.y * FSCALE) * INV_SCALE;
        v.z = rintf(v.z * FSCALE) * INV_SCALE;
        v.w = rintf(v.w * FSCALE) * INV_SCALE;
        *reinterpret_cast<float4*>(&sT[ci_rel * 132 + px4]) = v;
    }
    __syncthreads();

    uint4* Gp = G + ((size_t)n * G_NB + ciq * G_CIQB) / 16;
#pragma unroll
    for (int it = 0; it < 2; ++it) {
        int f = it * 256 + tid;
        int row_loc = f >> 7;
        int rem = f & 127;
        int w  = rem >> 2;
        int sg = rem & 3;
        int g  = sg ^ fsw(w);
        uint4 u;
        unsigned* up = &u.x;
#pragma unroll
        for (int j2 = 0; j2 < 4; ++j2) {
            unsigned lo = f16b(sT[(g * 8 + 2 * j2)     * 132 + row_loc * 32 + w]);
            unsigned hi = f16b(sT[(g * 8 + 2 * j2 + 1) * 132 + row_loc * 32 + w]);
            up[j2] = lo | (hi << 16);
        }
        int gr = rq * 4 + row_loc + 1;
        Gp[(gr * 32 + w) * 4 + sg] = u;
    }
    if (rq == 0 && tid < 128) Gp[tid] = make_uint4(0, 0, 0, 0);
    if (rq == 7 && tid < 128) Gp[33 * 128 + tid] = make_uint4(0, 0, 0, 0);
}

// conv via MFMA, barrier-free (unchanged from R11)
__global__ __launch_bounds__(256, 2) void conv_mfma(
    const uint4* __restrict__ G, const uint4* __restrict__ WF,
    unsigned* __restrict__ P)
{
    __shared__ uint4 sA[3072];
    const int tid  = threadIdx.x;
    const int lane = tid & 63;
    const int wid  = tid >> 6;
    const int b    = (blockIdx.x & 7) * 64 + (blockIdx.x >> 3);
    const int n    = b >> 3;
    const int q4   = b & 7;
    const int gsg  = lane >> 4;

    char* myL = (char*)sA + wid * 12288;
    const char* src = (const char*)G + (size_t)n * G_NB + (size_t)q4 * 4 * G_ROWB
                    + wid * 2048;

    f32x4 acc[8][2];
#pragma unroll
    for (int i = 0; i < 8; ++i)
#pragma unroll
        for (int j = 0; j < 2; ++j) acc[i][j] = (f32x4){0.f, 0.f, 0.f, 0.f};

    auto stage = [&](int ciq, int buf) {
        const char* s = src + ciq * G_CIQB;
#pragma unroll
        for (int rr = 0; rr < 3; ++rr)
#pragma unroll
            for (int k = 0; k < 2; ++k)
                gload_lds16(s + rr * 2048 + k * 1024 + lane * 16,
                            myL + buf * 6144 + rr * 2048 + k * 1024);
    };

    stage(0, 0);
    for (int ciq = 0; ciq < 4; ++ciq) {
        const int buf = ciq & 1;
        if (ciq < 3) {
            stage(ciq + 1, buf ^ 1);
            asm volatile("s_waitcnt vmcnt(6)" ::: "memory");
        } else {
            asm volatile("s_waitcnt vmcnt(0)" ::: "memory");
        }
        __builtin_amdgcn_sched_barrier(0);

        uint4 Brow[2][3];
        int pwh[2];
#pragma unroll
        for (int half = 0; half < 2; ++half) {
            pwh[half] = half * 16 + (lane & 15);
#pragma unroll
            for (int rr = 0; rr < 3; ++rr)
                Brow[half][rr] = *reinterpret_cast<const uint4*>(
                    myL + buf * 6144 + rr * 2048 + pwh[half] * 64
                    + ((gsg ^ fsw(pwh[half])) * 16));
        }
#pragma unroll
        for (int dh = 0; dh < 3; ++dh)
#pragma unroll
        for (int dw = 0; dw < 3; ++dw) {
            const uint4* wfp = WF + ((size_t)((dh * 3 + dw) * 4 + ciq)) * 512 + lane;
            f16x8 a[8];
#pragma unroll
            for (int cot = 0; cot < 8; ++cot)
                a[cot] = __builtin_bit_cast(f16x8, wfp[cot * 64]);
#pragma unroll
            for (int half = 0; half < 2; ++half) {
                uint4 braw;
                if (dw == 1) {
                    braw = Brow[half][dh];
                } else if (dw == 0) {
                    if (half == 0) braw = dpp4_shr(Brow[0][dh]);
                    else {
                        int w2 = pwh[1] - 1;
                        braw = *reinterpret_cast<const uint4*>(
                            myL + buf * 6144 + dh * 2048 + w2 * 64
                            + ((gsg ^ fsw(w2)) * 16));
                    }
                } else {
                    if (half == 1) braw = dpp4_shl(Brow[1][dh]);
                    else {
                        int w2 = pwh[0] + 1;
                        braw = *reinterpret_cast<const uint4*>(
                            myL + buf * 6144 + dh * 2048 + w2 * 64
                            + ((gsg ^ fsw(w2)) * 16));
                    }
                }
                f16x8 bf = __builtin_bit_cast(f16x8, braw);
#pragma unroll
                for (int cot = 0; cot < 8; ++cot)
                    acc[cot][half] = __builtin_amdgcn_mfma_f32_16x16x32_f16(
                        a[cot], bf, acc[cot][half], 0, 0, 0);
            }
        }
    }

    unsigned* Pn = P + (size_t)n * NPAIR * PLANE;
    const int r = q4 * 4 + wid;
#pragma unroll
    for (int cot = 0; cot < 8; ++cot) {
        int cp = cot * 8 + (lane >> 4) * 2;
#pragma unroll
        for (int p = 0; p < 2; ++p) {
            int px = r * 32 + p * 16 + (lane & 15);
            unsigned u01 = q16(acc[cot][p][0]) | (q16(acc[cot][p][1]) << 16);
            unsigned u23 = q16(acc[cot][p][2]) | (q16(acc[cot][p][3]) << 16);
            Pn[cp * PLANE + px] = u01;
            Pn[(cp + 1) * PLANE + px] = u23;
        }
    }
}

// ============================================================ fallback conv
__global__ __launch_bounds__(256, 2) void conv_shift_valu(
    const float* __restrict__ in, const float* __restrict__ wgt,
    unsigned* __restrict__ out)
{
    __shared__ __align__(16) float sIn[LDS_TOT];
    const int tid  = threadIdx.x;
    const int lane = tid & 63;
    const int wid  = tid >> 6;
    const int bid  = (blockIdx.x & 7) * 128 + (blockIdx.x >> 3);
    const int n    = bid >> 4;
    const int co0  = (bid & 15) * CO_CHUNK;
    const int r    = tid >> 3;
    const int c    = tid & 7;
    const int c0   = c * 4;
    const bool cz  = (c == 0), c7 = (c == 7);

    float acc[4][CO_CHUNK];
#pragma unroll
    for (int p = 0; p < 4; ++p)
#pragma unroll
        for (int co = 0; co < CO_CHUNK; ++co) acc[p][co] = 0.0f;

    const float* inN = in + (size_t)n * CIN * PLANE;
    for (int idx = tid; idx < 512; idx += 256) {
        int slot = idx >> 6, wq = idx & 63;
        sIn[slot * LPLANE + (wq < 32 ? wq : 1024 + wq)] = 0.0f;
    }
    stage_plane4(inN + wid * PLANE, sIn + wid * LPLANE, lane);
    __syncthreads();

    int cur = 0;
    for (int ci0 = 0; ci0 < CIN; ci0 += CI_CHUNK) {
        if (ci0 + CI_CHUNK < CIN)
            stage_plane4(inN + (size_t)(ci0 + CI_CHUNK + wid) * PLANE,
                         sIn + ((cur ^ 1) * CI_CHUNK + wid) * LPLANE, lane);
        const float* sb = sIn + cur * CI_CHUNK * LPLANE;
#pragma unroll
        for (int cc = 0; cc < CI_CHUNK; ++cc) {
            float w[3][6];
#pragma unroll
            for (int dh = 0; dh < 3; ++dh) {
                const float* sp = sb + cc * LPLANE + (r + dh) * 32 + c0;
                float4 qv = *reinterpret_cast<const float4*>(sp);
                qv.x = rintf(qv.x * FSCALE) * INV_SCALE;
                qv.y = rintf(qv.y * FSCALE) * INV_SCALE;
                qv.z = rintf(qv.z * FSCALE) * INV_SCALE;
                qv.w = rintf(qv.w * FSCALE) * INV_SCALE;
                float lf = dpp_prev(qv.w);
                float rt = dpp_next(qv.x);
                w[dh][0] = cz ? 0.0f : lf;
                w[dh][1] = qv.x; w[dh][2] = qv.y; w[dh][3] = qv.z; w[dh][4] = qv.w;
                w[dh][5] = c7 ? 0.0f : rt;
            }
            const float* wp = wgt + ((size_t)co0 * CIN + (ci0 + cc)) * 9;
#pragma unroll
            for (int co = 0; co < CO_CHUNK; ++co)
#pragma unroll
                for (int dh = 0; dh < 3; ++dh)
#pragma unroll
                    for (int dw = 0; dw < 3; ++dw) {
                        const float wvv = wp[(size_t)co * CIN * 9 + dh * 3 + dw];
#pragma unroll
                        for (int p = 0; p < 4; ++p)
                            acc[p][co] = fmaf(w[dh][p + dw], wvv, acc[p][co]);
                    }
        }
        __syncthreads();
        cur ^= 1;
    }
    unsigned* outP = out + ((size_t)n * NPAIR + co0 / 2) * PLANE + r * HW + c0;
#pragma unroll
    for (int pr = 0; pr < CO_CHUNK / 2; ++pr) {
        uint4 v;
        unsigned* vp = &v.x;
#pragma unroll
        for (int p = 0; p < 4; ++p)
            vp[p] = q16(acc[p][2 * pr]) | (q16(acc[p][2 * pr + 1]) << 16);
        *reinterpret_cast<uint4*>(&outP[pr * PLANE]) = v;
    }
}

__global__ __launch_bounds__(256) void bn_relu_inplace(
    float4* __restrict__ io, const float* __restrict__ scale,
    const float* __restrict__ bias)
{
    int i = blockIdx.x * 256 + threadIdx.x;
    int c = (i >> 8) & 127;
    float sc = scale[c], bs = bias[c];
    float4 v = io[i];
    v.x = fmaxf(fmaf(v.x, sc, bs), 0.0f);
    v.y = fmaxf(fmaf(v.y, sc, bs), 0.0f);
    v.z = fmaxf(fmaf(v.z, sc, bs), 0.0f);
    v.w = fmaxf(fmaf(v.w, sc, bs), 0.0f);
    io[i] = v;
}

// ============================================================ adder (R12)
// LDS: lead pad(4) + [guard row + 32 data rows] x 4 slots + final guard,
// stride 36 dwords, cols 32..35 = PZ. Window row = b128 + 2x b32, zero VALU.
// Reg-staged T14: global loads issued one step early; ds_write after barrier.
__global__ __launch_bounds__(256, 8) void adder_packed(
    const unsigned* __restrict__ in, const unsigned* __restrict__ wq,
    float* __restrict__ out, double* __restrict__ ssum, double* __restrict__ ssq)
{
    __shared__ __align__(16) unsigned sRaw[4 + 133 * ASTRIDE];   // 19168 B
    unsigned* sL = sRaw + 4;
    const int tid  = threadIdx.x;
    const int lane = tid & 63;
    const int bid  = (blockIdx.x & 7) * 256 + (blockIdx.x >> 3);  // 2048 blocks
    const int n    = bid >> 5;
    const int co0  = (bid & 31) * A_CO;
    const int r    = tid >> 3;            // image row 0..31
    const int c0   = (tid & 7) * 4;       // u32 col base
    const unsigned pz = PZ;

    // prefill guards: lead pad(4) + 5 guard rows(180) + guard cols(512) = 696
    for (int i = tid; i < 696; i += 256) {
        int addr;
        if (i < 4) {
            addr = i - 4;                                    // sRaw[0..3]
        } else if (i < 184) {
            int j = i - 4;
            addr = (j / 36) * 33 * ASTRIDE + (j % 36);       // rows 0,33,66,99,132
        } else {
            int j = i - 184;
            int dr = j >> 2, col = 32 + (j & 3);
            int s = dr >> 5, rr = dr & 31;
            addr = (s * 33 + 1 + rr) * ASTRIDE + col;
        }
        sL[addr] = pz;
    }

    unsigned acc[4][A_CO];
#pragma unroll
    for (int p = 0; p < 4; ++p)
#pragma unroll
        for (int co = 0; co < A_CO; ++co) acc[p][co] = 0u;

    const uint4* inN4 = (const uint4*)(in + (size_t)n * NPAIR * PLANE);

    auto wslot = [&](int sl, uint4 v) {
        *reinterpret_cast<uint4*>(&sL[(sl * 33 + 1 + r) * ASTRIDE + c0]) = v;
    };

    uint4 rg0 = inN4[tid], rg1 = inN4[256 + tid];
    wslot(0, rg0); wslot(1, rg1);
    rg0 = inN4[512 + tid]; rg1 = inN4[768 + tid];
    __syncthreads();

    for (int s = 0; s < NPAIR / 2; ++s) {            // 32 steps, 2 planes each
        const int bsl = (s & 1) * 2;
#pragma unroll
        for (int cc = 0; cc < 2; ++cc) {
            unsigned wi[3][6];
#pragma unroll
            for (int dh = 0; dh < 3; ++dh) {
                const unsigned* rowp = &sL[((bsl + cc) * 33 + r + dh) * ASTRIDE];
                wi[dh][0] = rowp[c0 - 1];             // guard col / lead pad
                uint4 qv = *reinterpret_cast<const uint4*>(&rowp[c0]);
                wi[dh][1] = qv.x; wi[dh][2] = qv.y;
                wi[dh][3] = qv.z; wi[dh][4] = qv.w;
                wi[dh][5] = rowp[c0 + 4];             // guard col at c0=28
            }
            const int cp = 2 * s + cc;
            const unsigned* wrow = wq + ((size_t)co0 * NPAIR + cp) * 9;
#pragma unroll
            for (int co = 0; co < A_CO; ++co)
#pragma unroll
                for (int dh = 0; dh < 3; ++dh)
#pragma unroll
                    for (int dw = 0; dw < 3; ++dw) {
                        const unsigned wv =
                            wrow[(size_t)co * NPAIR * 9 + dh * 3 + dw];
#pragma unroll
                        for (int p = 0; p < 4; ++p)
                            asm("v_sad_u16 %0, %1, %2, %0"
                                : "+v"(acc[p][co])
                                : "v"(wi[dh][p + dw]), "s"(wv));
                    }
        }
        if (s + 1 < NPAIR / 2) {                      // write next buf (T14 late)
            const int tsl = ((s + 1) & 1) * 2;
            wslot(tsl, rg0); wslot(tsl + 1, rg1);
        }
        if (s + 2 < NPAIR / 2) {                      // issue loads early
            rg0 = inN4[(2 * s + 4) * 256 + tid];
            rg1 = inN4[(2 * s + 5) * 256 + tid];
        }
        __syncthreads();
    }

    float* outP = out + ((size_t)n * COUT + co0) * PLANE + r * HW + c0;
#pragma unroll
    for (int co = 0; co < A_CO; ++co) {
        float y0 = -(float)acc[0][co] * INV_QS;
        float y1 = -(float)acc[1][co] * INV_QS;
        float y2 = -(float)acc[2][co] * INV_QS;
        float y3 = -(float)acc[3][co] * INV_QS;
        *reinterpret_cast<float4*>(&outP[co * PLANE]) = make_float4(y0, y1, y2, y3);
        float s = (y0 + y1) + (y2 + y3);
        float q = fmaf(y0, y0, y1 * y1) + fmaf(y2, y2, y3 * y3);
#pragma unroll
        for (int m = 32; m > 0; m >>= 1) {
            s += __shfl_xor(s, m, 64);
            q += __shfl_xor(q, m, 64);
        }
        if (lane == 0) {
            atomicAdd(&ssum[co0 + co], (double)s);
            atomicAdd(&ssq [co0 + co], (double)q);
        }
    }
}

// ============================================================ prep / BN (fallback)
__global__ __launch_bounds__(256) void prep_weights(
    const float* __restrict__ a1, const float* __restrict__ a2,
    unsigned* __restrict__ wqo, double* __restrict__ st)
{
    int i = blockIdx.x * 256 + threadIdx.x;          // < 147456
    if (blockIdx.x == 0) {
        st[threadIdx.x] = 0.0; st[threadIdx.x + 256] = 0.0;
    }
    int layer = i >= 73728;
    int j   = i - layer * 73728;
    int co  = j / 576;
    int rem = j - co * 576;
    int cp  = rem / 9;
    int tap = rem - cp * 9;
    const float* w = layer ? a2 : a1;
    float f0 = w[((size_t)co * CIN + 2 * cp) * 9 + tap];
    float f1 = w[((size_t)co * CIN + 2 * cp + 1) * 9 + tap];
    wqo[i] = q16(f0) | (q16(f1) << 16);
}

__global__ void finalize_bn(const double* __restrict__ ssum, const double* __restrict__ ssq,
                            const float* __restrict__ gamma, const float* __restrict__ beta,
                            float* __restrict__ scale, float* __restrict__ bias)
{
    int c = threadIdx.x;  // 128
    const double cnt = (double)NB * PLANE;
    double m   = ssum[c] / cnt;
    double var = ssq[c] / cnt - m * m;
    double rstd = 1.0 / sqrt(var + 1e-5);
    float sc = (float)((double)gamma[c] * rstd);
    scale[c] = sc;
    bias[c]  = beta[c] - (float)m * sc;
}

// BN2 + residual + ReLU, computing scale/bias from raw stats (1 ch per block)
__global__ __launch_bounds__(256) void bn_add_relu(
    float4* __restrict__ io, const float4* __restrict__ res,
    const double* __restrict__ st, const float* __restrict__ gamma,
    const float* __restrict__ beta)
{
    int i = blockIdx.x * 256 + threadIdx.x;
    int c = (i >> 8) & 127;
    double m   = st[c] / 65536.0;
    double var = st[128 + c] / 65536.0 - m * m;
    double rstd = 1.0 / sqrt(var + 1e-5);
    float sc = (float)((double)gamma[c] * rstd);
    float bs = beta[c] - (float)m * sc;
    float4 v = io[i];
    float4 x = res[i];
    v.x = fmaxf(fmaf(v.x, sc, bs) + x.x, 0.0f);
    v.y = fmaxf(fmaf(v.y, sc, bs) + x.y, 0.0f);
    v.z = fmaxf(fmaf(v.z, sc, bs) + x.z, 0.0f);
    v.w = fmaxf(fmaf(v.w, sc, bs) + x.w, 0.0f);
    io[i] = v;
}

// ============================================================ launch
extern "C" void kernel_launch(void* const* d_in, const int* in_sizes, int n_in,
                              void* d_out, int out_size, void* d_ws, size_t ws_size,
                              hipStream_t stream)
{
    const float* x    = (const float*)d_in[0];
    const float* wS1  = (const float*)d_in[1];
    const float* wA1  = (const float*)d_in[2];
    const float* g1   = (const float*)d_in[3];
    const float* b1   = (const float*)d_in[4];
    const float* wS2  = (const float*)d_in[5];
    const float* wA2  = (const float*)d_in[6];
    const float* g2   = (const float*)d_in[7];
    const float* b2   = (const float*)d_in[8];
    float* outp = (float*)d_out;

    char* ws = (char*)d_ws;
    const size_t MFMA_WS = 35788800;
    const bool mf = ws_size >= MFMA_WS;

    unsigned* P = (unsigned*)ws;                    // 16,777,216 B
    double* st; float* sb; unsigned* wq; char* Gb = nullptr; unsigned* WF = nullptr;
    if (mf) {
        Gb = ws + 16777216;                         // 17,825,792 B
        st = (double*)(ws + 34603008);
        sb = (float*)(ws + 34607104);
        wq = (unsigned*)(ws + 34609152);
        WF = (unsigned*)(ws + 35198976);
    } else {
        st = (double*)(ws + 16777216);
        sb = (float*)(st + 512);
        wq = (unsigned*)(sb + 512);
    }
    double* s1 = st,       *q1 = st + 128;
    double* s2 = st + 256, *q2 = st + 384;
    float* sc1 = sb,       *bi1 = sb + 128;
    float* sc2 = sb + 256, *bi2 = sb + 384;

    const int adderGrid = NB * (COUT / A_CO);             // 2048
    const int ewGrid    = (NB * COUT * PLANE / 4) / 256;  // 8192

    if (mf) {
        // 1: transform x (blocks 0..2047) + fused weight prep (2048..3199)
        transform_split<0><<<3200, 256, 0, stream>>>(
            x, nullptr, nullptr, nullptr, (uint4*)Gb,
            wA1, wA2, wS1, wS2, wq, WF, st);
        // 2-3: conv1 + adder1(stats1)
        conv_mfma<<<512, 256, 0, stream>>>((const uint4*)Gb, (const uint4*)WF, P);
        adder_packed<<<adderGrid, 256, 0, stream>>>(P, wq, outp, s1, q1);
        // 4: BN1(finalize in-kernel)+ReLU+round+pack -> G
        transform_split<1><<<2048, 256, 0, stream>>>(
            outp, s1, g1, b1, (uint4*)Gb,
            nullptr, nullptr, nullptr, nullptr, nullptr, nullptr, nullptr);
        // 5-6: conv2 + adder2(stats2)
        conv_mfma<<<512, 256, 0, stream>>>((const uint4*)Gb,
                                           (const uint4*)WF + 18432, P);
        adder_packed<<<adderGrid, 256, 0, stream>>>(P, wq + 73728, outp, s2, q2);
        // 7: BN2(finalize in-kernel) + residual + ReLU
        bn_add_relu<<<ewGrid, 256, 0, stream>>>((float4*)outp, (const float4*)x,
                                                s2, g2, b2);
    } else {
        prep_weights<<<576, 256, 0, stream>>>(wA1, wA2, wq, st);
        conv_shift_valu<<<1024, 256, 0, stream>>>(x, wS1, P);
        adder_packed<<<adderGrid, 256, 0, stream>>>(P, wq, outp, s1, q1);
        finalize_bn<<<1, 128, 0, stream>>>(s1, q1, g1, b1, sc1, bi1);
        bn_relu_inplace<<<ewGrid, 256, 0, stream>>>((float4*)outp, sc1, bi1);
        conv_shift_valu<<<1024, 256, 0, stream>>>(outp, wS2, P);
        adder_packed<<<adderGrid, 256, 0, stream>>>(P, wq + 73728, outp, s2, q2);
        bn_add_relu<<<ewGrid, 256, 0, stream>>>((float4*)outp, (const float4*)x,
                                                s2, g2, b2);
    }
}

// Round 13
// 412.417 us; speedup vs baseline: 1.0267x; 1.0267x over previous
//
#include <hip/hip_runtime.h>

// ShiftAddNet BasicBlock, N=64, C=planes=128, H=W=32, fp32.
// R13 = R12's launch fusion (7 kernels: prep fused into transform<0>,
// finalize_bn folded into transform<1> / bn_add_relu) + R11's adder
// (LPLANE guard-slot layout, DPP halo, conflicts=0 — measured best 182 us).

#define NB   64
#define CIN  128
#define HW   32
#define COUT 128
constexpr int PLANE    = HW * HW;        // 1024
constexpr int NPAIR    = CIN / 2;        // 64 packed ci-pair planes (adder)
constexpr int CI_CHUNK = 4;              // fallback conv only
constexpr int CO_CHUNK = 8;              // fallback conv only
constexpr int LPLANE   = 34 * 32;        // 1088 u32 per padded plane
constexpr int LDS_TOT  = 2 * CI_CHUNK * LPLANE;
constexpr int A_CO     = 4;              // adder co per block
constexpr float FSCALE    = 32768.0f;
constexpr float INV_SCALE = 1.0f / 32768.0f;
constexpr float QS     = 2048.0f;
constexpr float QB     = 32768.5f;
constexpr float INV_QS = 1.0f / 2048.0f;
constexpr unsigned PZ  = 0x80008000u;

// G (fp16 act) layout: [n][ciq(4)][gr(34)][w(32)][sg(4)][8 f16]
constexpr int G_ROWB   = 32 * 4 * 16;            // 2048 B per row
constexpr int G_CIQB   = 34 * G_ROWB;            // 69632 B
constexpr int G_NB     = 4 * G_CIQB;             // 278528 B per image

typedef _Float16 f16x8 __attribute__((ext_vector_type(8)));
typedef float    f32x4 __attribute__((ext_vector_type(4)));

#define GLOBAL_AS __attribute__((address_space(1)))
#define LDS_AS    __attribute__((address_space(3)))

__device__ __forceinline__ int fsw(int w) { return (w & 3) ^ ((w >> 2) & 3); }

__device__ __forceinline__ void gload_lds16(const void* g, void* l) {
    __builtin_amdgcn_global_load_lds((const GLOBAL_AS void*)g, (LDS_AS void*)l,
                                     16, 0, 0);
}
__device__ __forceinline__ float dpp_prev(float x) {
    return __int_as_float(__builtin_amdgcn_update_dpp(
        0, __float_as_int(x), 0x111, 0xF, 0xF, true));
}
__device__ __forceinline__ float dpp_next(float x) {
    return __int_as_float(__builtin_amdgcn_update_dpp(
        0, __float_as_int(x), 0x101, 0xF, 0xF, true));
}
__device__ __forceinline__ unsigned dpp_prev_u(unsigned x) {
    return (unsigned)__builtin_amdgcn_update_dpp(0, (int)x, 0x111, 0xF, 0xF, true);
}
__device__ __forceinline__ unsigned dpp_next_u(unsigned x) {
    return (unsigned)__builtin_amdgcn_update_dpp(0, (int)x, 0x101, 0xF, 0xF, true);
}
__device__ __forceinline__ uint4 dpp4_shr(uint4 v) {
    uint4 r;
    r.x = dpp_prev_u(v.x); r.y = dpp_prev_u(v.y);
    r.z = dpp_prev_u(v.z); r.w = dpp_prev_u(v.w);
    return r;
}
__device__ __forceinline__ uint4 dpp4_shl(uint4 v) {
    uint4 r;
    r.x = dpp_next_u(v.x); r.y = dpp_next_u(v.y);
    r.z = dpp_next_u(v.z); r.w = dpp_next_u(v.w);
    return r;
}
__device__ __forceinline__ void stage_plane4(const void* src, void* dst, int lane) {
#pragma unroll
    for (int i = 0; i < 4; ++i)
        gload_lds16((const char*)src + i * 1024 + lane * 16,
                    (char*)dst + 128 + i * 1024);
}
__device__ __forceinline__ unsigned q16(float a) {
    float t = fmaf(a, QS, QB);
    t = fminf(fmaxf(t, 0.0f), 65535.0f);
    return (unsigned)t;
}
__device__ __forceinline__ unsigned short f16b(float v) {
    return __builtin_bit_cast(unsigned short, (_Float16)v);
}

// ============================================================ MFMA conv path
// transform: fp32 NCHW (+optional in-kernel BN from raw stats) -> fp16 -> G.
// WITH_BN=0 variant also absorbs the weight-prep work in blocks >= 2048.
template <int WITH_BN>
__global__ __launch_bounds__(256) void transform_split(
    const float* __restrict__ in,
    const double* __restrict__ st, const float* __restrict__ gamma,
    const float* __restrict__ beta, uint4* __restrict__ G,
    const float* __restrict__ a1, const float* __restrict__ a2,
    const float* __restrict__ s1w, const float* __restrict__ s2w,
    unsigned* __restrict__ wqo, unsigned* __restrict__ WFd,
    double* __restrict__ stz)
{
    __shared__ float sT[32 * 132];
    __shared__ float sSC[32], sBI[32];
    const int tid = threadIdx.x;
    const int b   = blockIdx.x;

    if (!WITH_BN && b >= 2048) {             // fused weight prep + stats zero
        if (b == 2048) { stz[tid] = 0.0; stz[tid + 256] = 0.0; }
        int i = (b - 2048) * 256 + tid;      // < 294912
        if (i < 147456) {                    // adder weights (u16 pair)
            int layer = i >= 73728;
            int j   = i - layer * 73728;
            int co  = j / 576;
            int rem = j - co * 576;
            int cp  = rem / 9;
            int tap = rem - cp * 9;
            const float* w = layer ? a2 : a1;
            float f0 = w[((size_t)co * CIN + 2 * cp) * 9 + tap];
            float f1 = w[((size_t)co * CIN + 2 * cp + 1) * 9 + tap];
            wqo[i] = q16(f0) | (q16(f1) << 16);
        } else {                             // conv weights (fp16 A-frags)
            int j = i - 147456;
            int layer = j >= 73728;
            int idx = j - layer * 73728;
            int j2  = idx & 3;
            int l   = (idx >> 2) & 63;
            int cot = (idx >> 8) & 7;
            int ciq = (idx >> 11) & 3;
            int tap = idx >> 13;
            int ci  = ciq * 32 + (l >> 4) * 8 + j2 * 2;
            int co  = cot * 16 + (l & 15);
            const float* w = layer ? s2w : s1w;
            unsigned lo = f16b(w[((size_t)co * CIN + ci) * 9 + tap]);
            unsigned hi = f16b(w[((size_t)co * CIN + ci + 1) * 9 + tap]);
            WFd[layer * 73728 + idx] = lo | (hi << 16);
        }
        return;
    }

    const int n   = b >> 5;
    const int ciq = (b >> 3) & 3;
    const int rq  = b & 7;

    if (WITH_BN) {                           // in-kernel finalize_bn (32 ch)
        if (tid < 32) {
            int ch = ciq * 32 + tid;
            double m   = st[ch] / 65536.0;
            double var = st[128 + ch] / 65536.0 - m * m;
            double rstd = 1.0 / sqrt(var + 1e-5);
            float sc = (float)((double)gamma[ch] * rstd);
            sSC[tid] = sc;
            sBI[tid] = beta[ch] - (float)m * sc;
        }
        __syncthreads();
    }

#pragma unroll
    for (int it = 0; it < 4; ++it) {
        int flat = it * 256 + tid;
        int ci_rel = flat >> 5;
        int px4 = (flat & 31) * 4;
        const float* ap = in + ((size_t)(n * CIN + ciq * 32 + ci_rel)) * PLANE
                             + rq * 128 + px4;
        float4 v = *reinterpret_cast<const float4*>(ap);
        if (WITH_BN) {
            float sc = sSC[ci_rel], bs = sBI[ci_rel];
            v.x = fmaxf(fmaf(v.x, sc, bs), 0.0f);
            v.y = fmaxf(fmaf(v.y, sc, bs), 0.0f);
            v.z = fmaxf(fmaf(v.z, sc, bs), 0.0f);
            v.w = fmaxf(fmaf(v.w, sc, bs), 0.0f);
        }
        v.x = rintf(v.x * FSCALE) * INV_SCALE;
        v.y = rintf(v.y * FSCALE) * INV_SCALE;
        v.z = rintf(v.z * FSCALE) * INV_SCALE;
        v.w = rintf(v.w * FSCALE) * INV_SCALE;
        *reinterpret_cast<float4*>(&sT[ci_rel * 132 + px4]) = v;
    }
    __syncthreads();

    uint4* Gp = G + ((size_t)n * G_NB + ciq * G_CIQB) / 16;
#pragma unroll
    for (int it = 0; it < 2; ++it) {
        int f = it * 256 + tid;
        int row_loc = f >> 7;
        int rem = f & 127;
        int w  = rem >> 2;
        int sg = rem & 3;
        int g  = sg ^ fsw(w);
        uint4 u;
        unsigned* up = &u.x;
#pragma unroll
        for (int j2 = 0; j2 < 4; ++j2) {
            unsigned lo = f16b(sT[(g * 8 + 2 * j2)     * 132 + row_loc * 32 + w]);
            unsigned hi = f16b(sT[(g * 8 + 2 * j2 + 1) * 132 + row_loc * 32 + w]);
            up[j2] = lo | (hi << 16);
        }
        int gr = rq * 4 + row_loc + 1;
        Gp[(gr * 32 + w) * 4 + sg] = u;
    }
    if (rq == 0 && tid < 128) Gp[tid] = make_uint4(0, 0, 0, 0);
    if (rq == 7 && tid < 128) Gp[33 * 128 + tid] = make_uint4(0, 0, 0, 0);
}

// conv via MFMA, barrier-free (R11 structure)
__global__ __launch_bounds__(256, 2) void conv_mfma(
    const uint4* __restrict__ G, const uint4* __restrict__ WF,
    unsigned* __restrict__ P)
{
    __shared__ uint4 sA[3072];
    const int tid  = threadIdx.x;
    const int lane = tid & 63;
    const int wid  = tid >> 6;
    const int b    = (blockIdx.x & 7) * 64 + (blockIdx.x >> 3);
    const int n    = b >> 3;
    const int q4   = b & 7;
    const int gsg  = lane >> 4;

    char* myL = (char*)sA + wid * 12288;
    const char* src = (const char*)G + (size_t)n * G_NB + (size_t)q4 * 4 * G_ROWB
                    + wid * 2048;

    f32x4 acc[8][2];
#pragma unroll
    for (int i = 0; i < 8; ++i)
#pragma unroll
        for (int j = 0; j < 2; ++j) acc[i][j] = (f32x4){0.f, 0.f, 0.f, 0.f};

    auto stage = [&](int ciq, int buf) {
        const char* s = src + ciq * G_CIQB;
#pragma unroll
        for (int rr = 0; rr < 3; ++rr)
#pragma unroll
            for (int k = 0; k < 2; ++k)
                gload_lds16(s + rr * 2048 + k * 1024 + lane * 16,
                            myL + buf * 6144 + rr * 2048 + k * 1024);
    };

    stage(0, 0);
    for (int ciq = 0; ciq < 4; ++ciq) {
        const int buf = ciq & 1;
        if (ciq < 3) {
            stage(ciq + 1, buf ^ 1);
            asm volatile("s_waitcnt vmcnt(6)" ::: "memory");
        } else {
            asm volatile("s_waitcnt vmcnt(0)" ::: "memory");
        }
        __builtin_amdgcn_sched_barrier(0);

        uint4 Brow[2][3];
        int pwh[2];
#pragma unroll
        for (int half = 0; half < 2; ++half) {
            pwh[half] = half * 16 + (lane & 15);
#pragma unroll
            for (int rr = 0; rr < 3; ++rr)
                Brow[half][rr] = *reinterpret_cast<const uint4*>(
                    myL + buf * 6144 + rr * 2048 + pwh[half] * 64
                    + ((gsg ^ fsw(pwh[half])) * 16));
        }
#pragma unroll
        for (int dh = 0; dh < 3; ++dh)
#pragma unroll
        for (int dw = 0; dw < 3; ++dw) {
            const uint4* wfp = WF + ((size_t)((dh * 3 + dw) * 4 + ciq)) * 512 + lane;
            f16x8 a[8];
#pragma unroll
            for (int cot = 0; cot < 8; ++cot)
                a[cot] = __builtin_bit_cast(f16x8, wfp[cot * 64]);
#pragma unroll
            for (int half = 0; half < 2; ++half) {
                uint4 braw;
                if (dw == 1) {
                    braw = Brow[half][dh];
                } else if (dw == 0) {
                    if (half == 0) braw = dpp4_shr(Brow[0][dh]);
                    else {
                        int w2 = pwh[1] - 1;
                        braw = *reinterpret_cast<const uint4*>(
                            myL + buf * 6144 + dh * 2048 + w2 * 64
                            + ((gsg ^ fsw(w2)) * 16));
                    }
                } else {
                    if (half == 1) braw = dpp4_shl(Brow[1][dh]);
                    else {
                        int w2 = pwh[0] + 1;
                        braw = *reinterpret_cast<const uint4*>(
                            myL + buf * 6144 + dh * 2048 + w2 * 64
                            + ((gsg ^ fsw(w2)) * 16));
                    }
                }
                f16x8 bf = __builtin_bit_cast(f16x8, braw);
#pragma unroll
                for (int cot = 0; cot < 8; ++cot)
                    acc[cot][half] = __builtin_amdgcn_mfma_f32_16x16x32_f16(
                        a[cot], bf, acc[cot][half], 0, 0, 0);
            }
        }
    }

    unsigned* Pn = P + (size_t)n * NPAIR * PLANE;
    const int r = q4 * 4 + wid;
#pragma unroll
    for (int cot = 0; cot < 8; ++cot) {
        int cp = cot * 8 + (lane >> 4) * 2;
#pragma unroll
        for (int p = 0; p < 2; ++p) {
            int px = r * 32 + p * 16 + (lane & 15);
            unsigned u01 = q16(acc[cot][p][0]) | (q16(acc[cot][p][1]) << 16);
            unsigned u23 = q16(acc[cot][p][2]) | (q16(acc[cot][p][3]) << 16);
            Pn[cp * PLANE + px] = u01;
            Pn[(cp + 1) * PLANE + px] = u23;
        }
    }
}

// ============================================================ fallback conv
__global__ __launch_bounds__(256, 2) void conv_shift_valu(
    const float* __restrict__ in, const float* __restrict__ wgt,
    unsigned* __restrict__ out)
{
    __shared__ __align__(16) float sIn[LDS_TOT];
    const int tid  = threadIdx.x;
    const int lane = tid & 63;
    const int wid  = tid >> 6;
    const int bid  = (blockIdx.x & 7) * 128 + (blockIdx.x >> 3);
    const int n    = bid >> 4;
    const int co0  = (bid & 15) * CO_CHUNK;
    const int r    = tid >> 3;
    const int c    = tid & 7;
    const int c0   = c * 4;
    const bool cz  = (c == 0), c7 = (c == 7);

    float acc[4][CO_CHUNK];
#pragma unroll
    for (int p = 0; p < 4; ++p)
#pragma unroll
        for (int co = 0; co < CO_CHUNK; ++co) acc[p][co] = 0.0f;

    const float* inN = in + (size_t)n * CIN * PLANE;
    for (int idx = tid; idx < 512; idx += 256) {
        int slot = idx >> 6, wq = idx & 63;
        sIn[slot * LPLANE + (wq < 32 ? wq : 1024 + wq)] = 0.0f;
    }
    stage_plane4(inN + wid * PLANE, sIn + wid * LPLANE, lane);
    __syncthreads();

    int cur = 0;
    for (int ci0 = 0; ci0 < CIN; ci0 += CI_CHUNK) {
        if (ci0 + CI_CHUNK < CIN)
            stage_plane4(inN + (size_t)(ci0 + CI_CHUNK + wid) * PLANE,
                         sIn + ((cur ^ 1) * CI_CHUNK + wid) * LPLANE, lane);
        const float* sb = sIn + cur * CI_CHUNK * LPLANE;
#pragma unroll
        for (int cc = 0; cc < CI_CHUNK; ++cc) {
            float w[3][6];
#pragma unroll
            for (int dh = 0; dh < 3; ++dh) {
                const float* sp = sb + cc * LPLANE + (r + dh) * 32 + c0;
                float4 qv = *reinterpret_cast<const float4*>(sp);
                qv.x = rintf(qv.x * FSCALE) * INV_SCALE;
                qv.y = rintf(qv.y * FSCALE) * INV_SCALE;
                qv.z = rintf(qv.z * FSCALE) * INV_SCALE;
                qv.w = rintf(qv.w * FSCALE) * INV_SCALE;
                float lf = dpp_prev(qv.w);
                float rt = dpp_next(qv.x);
                w[dh][0] = cz ? 0.0f : lf;
                w[dh][1] = qv.x; w[dh][2] = qv.y; w[dh][3] = qv.z; w[dh][4] = qv.w;
                w[dh][5] = c7 ? 0.0f : rt;
            }
            const float* wp = wgt + ((size_t)co0 * CIN + (ci0 + cc)) * 9;
#pragma unroll
            for (int co = 0; co < CO_CHUNK; ++co)
#pragma unroll
                for (int dh = 0; dh < 3; ++dh)
#pragma unroll
                    for (int dw = 0; dw < 3; ++dw) {
                        const float wvv = wp[(size_t)co * CIN * 9 + dh * 3 + dw];
#pragma unroll
                        for (int p = 0; p < 4; ++p)
                            acc[p][co] = fmaf(w[dh][p + dw], wvv, acc[p][co]);
                    }
        }
        __syncthreads();
        cur ^= 1;
    }
    unsigned* outP = out + ((size_t)n * NPAIR + co0 / 2) * PLANE + r * HW + c0;
#pragma unroll
    for (int pr = 0; pr < CO_CHUNK / 2; ++pr) {
        uint4 v;
        unsigned* vp = &v.x;
#pragma unroll
        for (int p = 0; p < 4; ++p)
            vp[p] = q16(acc[p][2 * pr]) | (q16(acc[p][2 * pr + 1]) << 16);
        *reinterpret_cast<uint4*>(&outP[pr * PLANE]) = v;
    }
}

__global__ __launch_bounds__(256) void bn_relu_inplace(
    float4* __restrict__ io, const float* __restrict__ scale,
    const float* __restrict__ bias)
{
    int i = blockIdx.x * 256 + threadIdx.x;
    int c = (i >> 8) & 127;
    float sc = scale[c], bs = bias[c];
    float4 v = io[i];
    v.x = fmaxf(fmaf(v.x, sc, bs), 0.0f);
    v.y = fmaxf(fmaf(v.y, sc, bs), 0.0f);
    v.z = fmaxf(fmaf(v.z, sc, bs), 0.0f);
    v.w = fmaxf(fmaf(v.w, sc, bs), 0.0f);
    io[i] = v;
}

// ============================================================ adder (R11/R8 structure)
// 4 LDS plane slots (2 buffers x 2 planes), 8 blocks/CU, one barrier per step,
// DPP horizontal halo + cndmask edges, guard rows in slots. Conflicts = 0.
__global__ __launch_bounds__(256, 8) void adder_packed(
    const unsigned* __restrict__ in, const unsigned* __restrict__ wq,
    float* __restrict__ out, double* __restrict__ ssum, double* __restrict__ ssq)
{
    __shared__ __align__(16) unsigned sIn[4 * LPLANE];   // 17408 B
    const int tid  = threadIdx.x;
    const int lane = tid & 63;
    const int wid  = tid >> 6;
    const int bid  = (blockIdx.x & 7) * 256 + (blockIdx.x >> 3);  // 2048 blocks
    const int n    = bid >> 5;
    const int co0  = (bid & 31) * A_CO;
    const int r    = tid >> 3;
    const int c    = tid & 7;
    const int c0   = c * 4;
    const bool cz  = (c == 0), c7 = (c == 7);
    const unsigned pz = PZ;

    {   // guard rows of the 4 slots: 256 entries, one per thread
        int slot = tid >> 6, wqi = tid & 63;
        sIn[slot * LPLANE + (wqi < 32 ? wqi : 1024 + wqi)] = pz;
    }

    unsigned acc[4][A_CO];
#pragma unroll
    for (int p = 0; p < 4; ++p)
#pragma unroll
        for (int co = 0; co < A_CO; ++co) acc[p][co] = 0u;

    const unsigned* inN = in + (size_t)n * NPAIR * PLANE;

    // prefill both buffers: wave w stages plane w into slot w (planes 0..3)
    stage_plane4(inN + (size_t)wid * PLANE, sIn + wid * LPLANE, lane);
    __syncthreads();

    int cur = 0;
    for (int s = 0; s < NPAIR / 2; ++s) {            // 32 steps, 2 planes each
        if (s >= 1 && s + 1 < NPAIR / 2 && wid < 2)
            stage_plane4(inN + (size_t)(2 * (s + 1) + wid) * PLANE,
                         sIn + ((cur ^ 1) * 2 + wid) * LPLANE, lane);

        const unsigned* sb = sIn + cur * 2 * LPLANE;
#pragma unroll
        for (int cc = 0; cc < 2; ++cc) {
            unsigned wi[3][6];
#pragma unroll
            for (int dh = 0; dh < 3; ++dh) {
                const unsigned* sp = sb + cc * LPLANE + (r + dh) * 32 + c0;
                uint4 qv = *reinterpret_cast<const uint4*>(sp);
                unsigned lf = dpp_prev_u(qv.w);
                unsigned rt = dpp_next_u(qv.x);
                wi[dh][0] = cz ? pz : lf;
                wi[dh][1] = qv.x; wi[dh][2] = qv.y; wi[dh][3] = qv.z; wi[dh][4] = qv.w;
                wi[dh][5] = c7 ? pz : rt;
            }
            const int cp = 2 * s + cc;
            const unsigned* wrow = wq + ((size_t)co0 * NPAIR + cp) * 9;
#pragma unroll
            for (int co = 0; co < A_CO; ++co)
#pragma unroll
                for (int dh = 0; dh < 3; ++dh)
#pragma unroll
                    for (int dw = 0; dw < 3; ++dw) {
                        const unsigned wv =
                            wrow[(size_t)co * NPAIR * 9 + dh * 3 + dw];
#pragma unroll
                        for (int p = 0; p < 4; ++p)
                            asm("v_sad_u16 %0, %1, %2, %0"
                                : "+v"(acc[p][co])
                                : "v"(wi[dh][p + dw]), "s"(wv));
                    }
        }
        __syncthreads();
        cur ^= 1;
    }

    float* outP = out + ((size_t)n * COUT + co0) * PLANE + r * HW + c0;
#pragma unroll
    for (int co = 0; co < A_CO; ++co) {
        float y0 = -(float)acc[0][co] * INV_QS;
        float y1 = -(float)acc[1][co] * INV_QS;
        float y2 = -(float)acc[2][co] * INV_QS;
        float y3 = -(float)acc[3][co] * INV_QS;
        *reinterpret_cast<float4*>(&outP[co * PLANE]) = make_float4(y0, y1, y2, y3);
        float s = (y0 + y1) + (y2 + y3);
        float q = fmaf(y0, y0, y1 * y1) + fmaf(y2, y2, y3 * y3);
#pragma unroll
        for (int m = 32; m > 0; m >>= 1) {
            s += __shfl_xor(s, m, 64);
            q += __shfl_xor(q, m, 64);
        }
        if (lane == 0) {
            atomicAdd(&ssum[co0 + co], (double)s);
            atomicAdd(&ssq [co0 + co], (double)q);
        }
    }
}

// ============================================================ prep / BN (fallback)
__global__ __launch_bounds__(256) void prep_weights(
    const float* __restrict__ a1, const float* __restrict__ a2,
    unsigned* __restrict__ wqo, double* __restrict__ st)
{
    int i = blockIdx.x * 256 + threadIdx.x;          // < 147456
    if (blockIdx.x == 0) {
        st[threadIdx.x] = 0.0; st[threadIdx.x + 256] = 0.0;
    }
    int layer = i >= 73728;
    int j   = i - layer * 73728;
    int co  = j / 576;
    int rem = j - co * 576;
    int cp  = rem / 9;
    int tap = rem - cp * 9;
    const float* w = layer ? a2 : a1;
    float f0 = w[((size_t)co * CIN + 2 * cp) * 9 + tap];
    float f1 = w[((size_t)co * CIN + 2 * cp + 1) * 9 + tap];
    wqo[i] = q16(f0) | (q16(f1) << 16);
}

__global__ void finalize_bn(const double* __restrict__ ssum, const double* __restrict__ ssq,
                            const float* __restrict__ gamma, const float* __restrict__ beta,
                            float* __restrict__ scale, float* __restrict__ bias)
{
    int c = threadIdx.x;  // 128
    const double cnt = (double)NB * PLANE;
    double m   = ssum[c] / cnt;
    double var = ssq[c] / cnt - m * m;
    double rstd = 1.0 / sqrt(var + 1e-5);
    float sc = (float)((double)gamma[c] * rstd);
    scale[c] = sc;
    bias[c]  = beta[c] - (float)m * sc;
}

// BN2 + residual + ReLU, computing scale/bias from raw stats (1 ch per block)
__global__ __launch_bounds__(256) void bn_add_relu(
    float4* __restrict__ io, const float4* __restrict__ res,
    const double* __restrict__ st, const float* __restrict__ gamma,
    const float* __restrict__ beta)
{
    int i = blockIdx.x * 256 + threadIdx.x;
    int c = (i >> 8) & 127;
    double m   = st[c] / 65536.0;
    double var = st[128 + c] / 65536.0 - m * m;
    double rstd = 1.0 / sqrt(var + 1e-5);
    float sc = (float)((double)gamma[c] * rstd);
    float bs = beta[c] - (float)m * sc;
    float4 v = io[i];
    float4 x = res[i];
    v.x = fmaxf(fmaf(v.x, sc, bs) + x.x, 0.0f);
    v.y = fmaxf(fmaf(v.y, sc, bs) + x.y, 0.0f);
    v.z = fmaxf(fmaf(v.z, sc, bs) + x.z, 0.0f);
    v.w = fmaxf(fmaf(v.w, sc, bs) + x.w, 0.0f);
    io[i] = v;
}

// ============================================================ launch
extern "C" void kernel_launch(void* const* d_in, const int* in_sizes, int n_in,
                              void* d_out, int out_size, void* d_ws, size_t ws_size,
                              hipStream_t stream)
{
    const float* x    = (const float*)d_in[0];
    const float* wS1  = (const float*)d_in[1];
    const float* wA1  = (const float*)d_in[2];
    const float* g1   = (const float*)d_in[3];
    const float* b1   = (const float*)d_in[4];
    const float* wS2  = (const float*)d_in[5];
    const float* wA2  = (const float*)d_in[6];
    const float* g2   = (const float*)d_in[7];
    const float* b2   = (const float*)d_in[8];
    float* outp = (float*)d_out;

    char* ws = (char*)d_ws;
    const size_t MFMA_WS = 35788800;
    const bool mf = ws_size >= MFMA_WS;

    unsigned* P = (unsigned*)ws;                    // 16,777,216 B
    double* st; float* sb; unsigned* wq; char* Gb = nullptr; unsigned* WF = nullptr;
    if (mf) {
        Gb = ws + 16777216;                         // 17,825,792 B
        st = (double*)(ws + 34603008);
        sb = (float*)(ws + 34607104);
        wq = (unsigned*)(ws + 34609152);
        WF = (unsigned*)(ws + 35198976);
    } else {
        st = (double*)(ws + 16777216);
        sb = (float*)(st + 512);
        wq = (unsigned*)(sb + 512);
    }
    double* s1 = st,       *q1 = st + 128;
    double* s2 = st + 256, *q2 = st + 384;
    float* sc1 = sb,       *bi1 = sb + 128;
    float* sc2 = sb + 256, *bi2 = sb + 384;

    const int adderGrid = NB * (COUT / A_CO);             // 2048
    const int ewGrid    = (NB * COUT * PLANE / 4) / 256;  // 8192

    if (mf) {
        // 1: transform x (blocks 0..2047) + fused weight prep (2048..3199)
        transform_split<0><<<3200, 256, 0, stream>>>(
            x, nullptr, nullptr, nullptr, (uint4*)Gb,
            wA1, wA2, wS1, wS2, wq, WF, st);
        // 2-3: conv1 + adder1(stats1)
        conv_mfma<<<512, 256, 0, stream>>>((const uint4*)Gb, (const uint4*)WF, P);
        adder_packed<<<adderGrid, 256, 0, stream>>>(P, wq, outp, s1, q1);
        // 4: BN1(finalize in-kernel)+ReLU+round+pack -> G
        transform_split<1><<<2048, 256, 0, stream>>>(
            outp, s1, g1, b1, (uint4*)Gb,
            nullptr, nullptr, nullptr, nullptr, nullptr, nullptr, nullptr);
        // 5-6: conv2 + adder2(stats2)
        conv_mfma<<<512, 256, 0, stream>>>((const uint4*)Gb,
                                           (const uint4*)WF + 18432, P);
        adder_packed<<<adderGrid, 256, 0, stream>>>(P, wq + 73728, outp, s2, q2);
        // 7: BN2(finalize in-kernel) + residual + ReLU
        bn_add_relu<<<ewGrid, 256, 0, stream>>>((float4*)outp, (const float4*)x,
                                                s2, g2, b2);
    } else {
        prep_weights<<<576, 256, 0, stream>>>(wA1, wA2, wq, st);
        conv_shift_valu<<<1024, 256, 0, stream>>>(x, wS1, P);
        adder_packed<<<adderGrid, 256, 0, stream>>>(P, wq, outp, s1, q1);
        finalize_bn<<<1, 128, 0, stream>>>(s1, q1, g1, b1, sc1, bi1);
        bn_relu_inplace<<<ewGrid, 256, 0, stream>>>((float4*)outp, sc1, bi1);
        conv_shift_valu<<<1024, 256, 0, stream>>>(outp, wS2, P);
        adder_packed<<<adderGrid, 256, 0, stream>>>(P, wq + 73728, outp, s2, q2);
        bn_add_relu<<<ewGrid, 256, 0, stream>>>((float4*)outp, (const float4*)x,
                                                s2, g2, b2);
    }
}